// Round 11
// baseline (1221.636 us; speedup 1.0000x reference)
//
#include <hip/hip_runtime.h>
#include <float.h>

#define DECAY 0.99f
#define EPS 1e-5f
#define NROWS 65536
#define DIM 256
#define NEMB 1024
#define CH 64            // rows per sub-chunk in segmented reduction
#define MAXSUB 2048      // NROWS/CH + NEMB upper bound on total sub-chunks
#define WND 1.6f         // certificate window: > 2 * (2^-9 * ||x||max * ||e||max)

#define GLOBAL_AS __attribute__((address_space(1)))
#define LOCAL_AS  __attribute__((address_space(3)))

typedef _Float16 f16;
typedef _Float16 half8 __attribute__((ext_vector_type(8)));
typedef float f32x4 __attribute__((ext_vector_type(4)));

// ---------- K0a: ||e_k||^2 per code + zero counts + zero nflag ----------
__global__ __launch_bounds__(256) void k_enorm(const float* __restrict__ embed,
                                               float* __restrict__ enorm2,
                                               int* __restrict__ counts,
                                               int* __restrict__ nflag) {
    int kk = threadIdx.x & 63;
    int dg = threadIdx.x >> 6;              // 0..3
    int k  = blockIdx.x * 64 + kk;          // 16 blocks * 64 = 1024 codes
    float s = 0.f;
    for (int d = dg; d < DIM; d += 4) {
        float v = embed[(size_t)d * NEMB + k];
        s = fmaf(v, v, s);
    }
    __shared__ float red[4][64];
    red[dg][kk] = s;
    __syncthreads();
    if (dg == 0) enorm2[k] = red[0][kk] + red[1][kk] + red[2][kk] + red[3][kk];
    int gt = blockIdx.x * 256 + threadIdx.x;
    if (gt < NEMB) counts[gt] = 0;
    if (blockIdx.x == 0 && threadIdx.x == 0) nflag[0] = 0;
}

// ---------- K0b: fused transpose (embedT fp32) + f16-hi split (ehT [1024][256]) ----------
__global__ __launch_bounds__(256) void k_prep(const float* __restrict__ embed,
                                              float* __restrict__ embedT,
                                              f16* __restrict__ ehT) {
    __shared__ float tile[32][33];           // [d-local][c-local]
    int c0 = blockIdx.x * 32, d0 = blockIdx.y * 32;
    int tx = threadIdx.x, ty = threadIdx.y;  // 32 x 8
#pragma unroll
    for (int i = 0; i < 4; i++)
        tile[ty + 8 * i][tx] = embed[(size_t)(d0 + ty + 8 * i) * NEMB + c0 + tx];
    __syncthreads();
#pragma unroll
    for (int i = 0; i < 4; i++) {
        int c = c0 + ty + 8 * i;
        int d = d0 + tx;
        float v = tile[tx][ty + 8 * i];
        embedT[(size_t)c * DIM + d] = v;
        ehT[(size_t)c * 256 + d] = (f16)v;
    }
}

// ---------- K1: MFMA GEMM-argmin v9: 1-term f16 + 2nd-best certificate ----------
// 256 threads = 4 waves; block = 64 rows x 1024 cols (4 slabs of 256). 2 blocks/CU.
// A resident: [64 rows][256 f16] = 32KB, byte = row*512 + ((slot*16)^((row&7)<<4)).
// B: double-buffered 16KB tiles (256 cols x 32 k) via global_load_lds
//    (linear dest, pre-swizzled source: slot_log=(l&3)^((l>>3)&3)),
//    read at byte = col*64 + ((lkh*16) ^ (((col>>1)&3)<<4)).   [R6-proven layouts]
#define LDS_A  0        // 32KB
#define LDS_B0 32768    // 16KB (PV/PI/P2 overlay after the loop)
#define LDS_B1 49152    // 16KB
#define LDS_SZ 65536

__global__ __launch_bounds__(256, 2) void k_argmin_mfma(const float* __restrict__ input,
                                                        const f16* __restrict__ ehT,
                                                        const float* __restrict__ enorm2,
                                                        int* __restrict__ ind,
                                                        float* __restrict__ out_ind,
                                                        int* __restrict__ counts,
                                                        unsigned char* __restrict__ flags) {
    __shared__ char lds[LDS_SZ];
    const int tid  = threadIdx.x;
    const int lane = tid & 63;
    const int w    = tid >> 6;        // wave 0..3: cols w*64 within each 256-slab
    const int rb   = blockIdx.x * 64;
    const int l15  = lane & 15;
    const int lkh  = lane >> 4;       // 0..3
    const int slot_log   = (lane & 3) ^ ((lane >> 3) & 3);
    const int gl_laneoff = (lane >> 2) * 256 + slot_log * 8;   // f16 units (row len 256)

    // preload e2 for all 4 slabs -> regs (no VMEM in the loop)
    float e2a[4][4];
#pragma unroll
    for (int s = 0; s < 4; ++s)
#pragma unroll
        for (int fc = 0; fc < 4; ++fc)
            e2a[s][fc] = enorm2[s * 256 + w * 64 + fc * 16 + l15];

    // ---- issue B tile 0 prefetch (ct=0, kt=0) ----
#pragma unroll
    for (int i = 0; i < 4; i++) {
        int chunk = w * 4 + i;                           // 16 chunks of 16 cols
        const f16* src = ehT + (size_t)chunk * 4096 + gl_laneoff;
        __builtin_amdgcn_global_load_lds((const GLOBAL_AS unsigned*)src,
            (LOCAL_AS unsigned*)(lds + LDS_B0 + chunk * 1024), 16, 0, 0);
    }

    // ---- stage A once: 64 rows x 256 d fp32 -> f16 hi, swizzled ----
#pragma unroll
    for (int it4 = 0; it4 < 4; it4++) {
        int task = tid + 256 * it4;          // 0..1023
        int row = task >> 4, ch = task & 15; // ch = 16-d chunk
        const float4* g = (const float4*)(input + (size_t)(rb + row) * DIM + ch * 16);
        float fv[16];
        *(float4*)(fv + 0)  = g[0];
        *(float4*)(fv + 4)  = g[1];
        *(float4*)(fv + 8)  = g[2];
        *(float4*)(fv + 12) = g[3];
        half8 hh[2];
#pragma unroll
        for (int u = 0; u < 2; u++)
#pragma unroll
            for (int e = 0; e < 8; e++) hh[u][e] = (f16)fv[u * 8 + e];
        int rbase = row * 512;
        int sw = (row & 7) << 4;
        *(half8*)(lds + LDS_A + rbase + (((ch * 2    ) * 16) ^ sw)) = hh[0];
        *(half8*)(lds + LDS_A + rbase + (((ch * 2 + 1) * 16) ^ sw)) = hh[1];
    }
    __syncthreads();   // A staged + B0 landed

    float bv[16], b2[16];
    int   bi[16];
#pragma unroll
    for (int q = 0; q < 16; q++) { bv[q] = FLT_MAX; b2[q] = FLT_MAX; bi[q] = 0x7fffffff; }

    f32x4 acc[4][4];
    int p = 0;
    for (int it = 0; it < 32; ++it) {
        const int ct = it >> 3, kt = it & 7;
        if (kt == 0) {
#pragma unroll
            for (int fr = 0; fr < 4; fr++)
#pragma unroll
                for (int fc = 0; fc < 4; fc++) acc[fr][fc] = (f32x4){0.f, 0.f, 0.f, 0.f};
        }
        // ---- issue next-tile prefetch into the idle buffer ----
        if (it < 31) {
            int itn = it + 1;
            int ct2 = itn >> 3, kt2 = itn & 7;
            const f16* base = ehT + (size_t)ct2 * 65536 + kt2 * 32 + gl_laneoff;
            char* dstb = lds + (p ? LDS_B0 : LDS_B1);
#pragma unroll
            for (int i = 0; i < 4; i++) {
                int chunk = w * 4 + i;
                __builtin_amdgcn_global_load_lds(
                    (const GLOBAL_AS unsigned*)(base + (size_t)chunk * 4096),
                    (LOCAL_AS unsigned*)(dstb + chunk * 1024), 16, 0, 0);
            }
        }
        // ---- frags + MFMA on current tile (buf p) ----
        const char* Bb = lds + (p ? LDS_B1 : LDS_B0);
        half8 af[4], bf[4];
#pragma unroll
        for (int f = 0; f < 4; f++) {
            int row = f * 16 + l15;
            af[f] = *(const half8*)(lds + LDS_A + row * 512 +
                                    (((kt * 4 + lkh) * 16) ^ ((row & 7) << 4)));
        }
#pragma unroll
        for (int f = 0; f < 4; f++) {
            int col = w * 64 + f * 16 + l15;
            bf[f] = *(const half8*)(Bb + col * 64 + ((lkh * 16) ^ (((col >> 1) & 3) << 4)));
        }
        __builtin_amdgcn_s_setprio(1);
#pragma unroll
        for (int fr = 0; fr < 4; fr++)
#pragma unroll
            for (int fc = 0; fc < 4; fc++)
                acc[fr][fc] = __builtin_amdgcn_mfma_f32_16x16x32_f16(
                    af[fr], bf[fc], acc[fr][fc], 0, 0, 0);
        __builtin_amdgcn_s_setprio(0);
        // ---- slab epilogue: running (best, 2nd-best) per row ----
        if (kt == 7) {
#pragma unroll
            for (int fc = 0; fc < 4; fc++) {
                int col = ct * 256 + w * 64 + fc * 16 + l15;
                float e2 = e2a[ct][fc];
#pragma unroll
                for (int fr = 0; fr < 4; fr++)
#pragma unroll
                    for (int r = 0; r < 4; r++) {
                        float s = fmaf(-2.f, acc[fr][fc][r], e2);
                        int q = fr * 4 + r;
                        if (s < bv[q]) { b2[q] = bv[q]; bv[q] = s; bi[q] = col; }
                        else if (s < b2[q]) b2[q] = s;
                    }
            }
        }
        __syncthreads();
        p ^= 1;
    }

    // ---- cross-lane triple reduce over the 16 col-lanes ----
#pragma unroll
    for (int q = 0; q < 16; q++) {
        float v1 = bv[q], v2 = b2[q]; int i1 = bi[q];
#pragma unroll
        for (int m = 1; m <= 8; m <<= 1) {
            float ov1 = __shfl_xor(v1, m, 64);
            int   oi1 = __shfl_xor(i1, m, 64);
            float ov2 = __shfl_xor(v2, m, 64);
            if (ov1 < v1 || (ov1 == v1 && oi1 < i1)) {
                v2 = fminf(v1, ov2); v1 = ov1; i1 = oi1;
            } else {
                v2 = fminf(v2, ov1);
            }
        }
        bv[q] = v1; bi[q] = i1; b2[q] = v2;
    }
    float* PV = (float*)(lds + LDS_B0);          // [64][4]
    int*   PI = (int*)(lds + LDS_B0 + 1024);     // [64][4]
    float* P2 = (float*)(lds + LDS_B0 + 2048);   // [64][4]
    if (l15 == 0) {
#pragma unroll
        for (int fr = 0; fr < 4; fr++)
#pragma unroll
            for (int r = 0; r < 4; r++) {
                int rrow = fr * 16 + lkh * 4 + r;
                PV[rrow * 4 + w] = bv[fr * 4 + r];
                PI[rrow * 4 + w] = bi[fr * 4 + r];
                P2[rrow * 4 + w] = b2[fr * 4 + r];
            }
    }
    __syncthreads();
    if (tid < 64) {
        float v1 = PV[tid * 4]; int i1 = PI[tid * 4]; float v2 = P2[tid * 4];
#pragma unroll
        for (int t = 1; t < 4; t++) {
            float ov1 = PV[tid * 4 + t]; int oi1 = PI[tid * 4 + t]; float ov2 = P2[tid * 4 + t];
            if (ov1 < v1 || (ov1 == v1 && oi1 < i1)) {
                v2 = fminf(v1, ov2); v1 = ov1; i1 = oi1;
            } else {
                v2 = fminf(v2, ov1);
            }
        }
        int fl = (v2 - v1 <= WND) ? 1 : 0;
        ind[rb + tid] = i1;
        out_ind[rb + tid] = (float)i1;
        flags[rb + tid] = (unsigned char)fl;
        if (!fl) atomicAdd(&counts[i1], 1);   // flagged rows counted in k_fix
    }
}

// ---------- K1b: compact flagged rows (order-free; per-row results independent) ----------
__global__ __launch_bounds__(256) void k_compact(const unsigned char* __restrict__ flags,
                                                 int* __restrict__ nflag,
                                                 int* __restrict__ flaglist) {
    int i = blockIdx.x * 256 + threadIdx.x;
    if (flags[i]) { int p = atomicAdd(nflag, 1); flaglist[p] = i; }
}

// ---------- K1c: exact fp32 re-resolve of flagged rows, 8 rows per embed scan ----------
__global__ __launch_bounds__(256) void k_fix(const float* __restrict__ input,
                                             const float* __restrict__ embed,
                                             const float* __restrict__ enorm2,
                                             const int* __restrict__ flaglist,
                                             const int* __restrict__ nflag,
                                             int* __restrict__ ind,
                                             float* __restrict__ out_ind,
                                             int* __restrict__ counts) {
    __shared__ float xs[8][256];
    __shared__ float rv[256];
    __shared__ int   ri[256];
    const int t = threadIdx.x;
    const int total = nflag[0];
    for (int base = blockIdx.x * 8; base < total; base += 64 * 8) {
        const int nr = min(8, total - base);
        __syncthreads();
        for (int j = 0; j < nr; j++) {
            int row = flaglist[base + j];
            xs[j][t] = input[(size_t)row * DIM + t];
        }
        __syncthreads();
        float best[8]; int bidx[8];
#pragma unroll
        for (int j = 0; j < 8; j++) { best[j] = FLT_MAX; bidx[j] = 0x7fffffff; }
        for (int cc = 0; cc < 4; cc++) {
            int c = cc * 256 + t;
            float s[8];
#pragma unroll
            for (int j = 0; j < 8; j++) s[j] = 0.f;
            for (int d = 0; d < 256; d++) {
                float e = embed[(size_t)d * NEMB + c];   // coalesced across threads
#pragma unroll
                for (int j = 0; j < 8; j++) s[j] = fmaf(xs[j][d], e, s[j]);
            }
            float e2 = enorm2[c];
#pragma unroll
            for (int j = 0; j < 8; j++) {
                float dist = fmaf(-2.f, s[j], e2);
                if (dist < best[j]) { best[j] = dist; bidx[j] = c; }  // cc asc => lowest idx on tie
            }
        }
        for (int j = 0; j < nr; j++) {
            rv[t] = best[j]; ri[t] = bidx[j];
            __syncthreads();
            for (int off = 128; off > 0; off >>= 1) {
                if (t < off) {
                    float v = rv[t + off]; int i2 = ri[t + off];
                    if (v < rv[t] || (v == rv[t] && i2 < ri[t])) { rv[t] = v; ri[t] = i2; }
                }
                __syncthreads();
            }
            if (t == 0) {
                int row = flaglist[base + j];
                ind[row] = ri[0];
                out_ind[row] = (float)ri[0];
                atomicAdd(&counts[ri[0]], 1);
            }
            __syncthreads();
        }
    }
}

// ---------- K2: quantize_st output + per-block diff partials ----------
__global__ __launch_bounds__(256) void k_quant(const float* __restrict__ input,
                                               const float* __restrict__ embedT,
                                               const int* __restrict__ ind,
                                               float* __restrict__ out_q,
                                               float* __restrict__ partials) {
    const int tid = threadIdx.x;
    const unsigned gid = blockIdx.x * 256 + tid;
    float s = 0.f;
#pragma unroll
    for (int j = 0; j < 8; j++) {
        size_t i4 = (size_t)gid + (size_t)j * 524288u;   // 4194304 float4 total
        int row = (int)(i4 >> 6);
        int d4  = (int)(i4 & 63);
        float4 iv = *reinterpret_cast<const float4*>(input + i4 * 4);
        int k = ind[row];
        float4 qv = *reinterpret_cast<const float4*>(embedT + (size_t)k * DIM + d4 * 4);
        float dx = qv.x - iv.x, dy = qv.y - iv.y, dz = qv.z - iv.z, dw = qv.w - iv.w;
        float4 ov;
        ov.x = iv.x + dx; ov.y = iv.y + dy; ov.z = iv.z + dz; ov.w = iv.w + dw;
        *reinterpret_cast<float4*>(out_q + i4 * 4) = ov;
        s += dx * dx + dy * dy + dz * dz + dw * dw;
    }
    __shared__ float red[256];
    red[tid] = s;
    __syncthreads();
    for (int off = 128; off > 0; off >>= 1) {
        if (tid < off) red[tid] += red[tid + off];
        __syncthreads();
    }
    if (tid == 0) partials[blockIdx.x] = red[0];
}

// ---------- K4: diff finalize + scans + ncs, n, cs ----------
__global__ __launch_bounds__(1024) void k_scan(const int* __restrict__ counts,
                                               const float* __restrict__ cluster_size,
                                               const float* __restrict__ qpartials,
                                               int* __restrict__ offsets,
                                               int* __restrict__ cursor,
                                               int* __restrict__ substart,
                                               float* __restrict__ out_ncs,
                                               float* __restrict__ cs,
                                               float* __restrict__ out_diff) {
    __shared__ int sh[NEMB];
    __shared__ float shf[NEMB];
    int tid = threadIdx.x;
    shf[tid] = qpartials[tid] + qpartials[tid + 1024];
    __syncthreads();
    for (int off = 512; off > 0; off >>= 1) {
        if (tid < off) shf[tid] += shf[tid + off];
        __syncthreads();
    }
    if (tid == 0) out_diff[0] = shf[0] / 16777216.0f;
    __syncthreads();
    int c = counts[tid];
    sh[tid] = c;
    __syncthreads();
    for (int off = 1; off < NEMB; off <<= 1) {
        int t = (tid >= off) ? sh[tid - off] : 0;
        __syncthreads();
        sh[tid] += t;
        __syncthreads();
    }
    int excl = sh[tid] - c;
    offsets[tid] = excl;
    cursor[tid]  = excl;
    int sc = (c + CH - 1) / CH;
    __syncthreads();
    sh[tid] = sc;
    __syncthreads();
    for (int off = 1; off < NEMB; off <<= 1) {
        int t = (tid >= off) ? sh[tid - off] : 0;
        __syncthreads();
        sh[tid] += t;
        __syncthreads();
    }
    substart[tid] = sh[tid] - sc;
    if (tid == NEMB - 1) substart[NEMB] = sh[tid];
    float ncs = cluster_size[tid] * DECAY + (1.f - DECAY) * (float)c;
    out_ncs[tid] = ncs;
    shf[tid] = ncs;
    __syncthreads();
    for (int off = 512; off > 0; off >>= 1) {
        if (tid < off) shf[tid] += shf[tid + off];
        __syncthreads();
    }
    float n = shf[0];
    cs[tid] = (ncs + EPS) / (n + NEMB * EPS) * n;
}

// ---------- K5: scatter rows by cluster ----------
__global__ __launch_bounds__(256) void k_scatter(const int* __restrict__ ind,
                                                 int* __restrict__ cursor,
                                                 int* __restrict__ sorted) {
    int i = blockIdx.x * 256 + threadIdx.x;
    int k = ind[i];
    int pos = atomicAdd(&cursor[k], 1);
    sorted[pos] = i;
}

// ---------- K6a: balanced partial sums. block = one 64-row sub-chunk ----------
__global__ __launch_bounds__(256) void k_psum(const float* __restrict__ input,
                                              const int* __restrict__ sorted,
                                              const int* __restrict__ counts,
                                              const int* __restrict__ offsets,
                                              const int* __restrict__ substart,
                                              float* __restrict__ partial) {
    const int b = blockIdx.x;
    if (b >= substart[NEMB]) return;
    int lo = 0, hi = NEMB;
    while (hi - lo > 1) {
        int mid = (lo + hi) >> 1;
        if (substart[mid] <= b) lo = mid; else hi = mid;
    }
    const int k     = lo;
    const int chunk = b - substart[k];
    const int cnt   = counts[k];
    const int base  = offsets[k] + chunk * CH;
    const int lim   = min(CH, cnt - chunk * CH);
    const int d     = threadIdx.x;
    float s = 0.f;
    for (int i = 0; i < lim; i++) {
        int row = sorted[base + i];
        s += input[(size_t)row * DIM + d];
    }
    partial[(size_t)b * DIM + d] = s;
}

// ---------- K6b: per-cluster combine (fixed order) + EMA + new_embed ----------
__global__ __launch_bounds__(256) void k_ema(const float* __restrict__ partial,
                                             const float* __restrict__ embed_avg,
                                             const int* __restrict__ substart,
                                             const float* __restrict__ cs,
                                             float* __restrict__ out_navg,
                                             float* __restrict__ out_nembed) {
    const int d = blockIdx.x;
    const int t = threadIdx.x;
#pragma unroll
    for (int i = 0; i < 4; i++) {
        int k = t + 256 * i;
        int s0 = substart[k], s1 = substart[k + 1];
        float s = 0.f;
        for (int sub = s0; sub < s1; sub++)
            s += partial[(size_t)sub * DIM + d];
        float navg = embed_avg[(size_t)d * NEMB + k] * (DECAY * DECAY) + (1.f - DECAY) * s;
        out_navg[(size_t)d * NEMB + k] = navg;
        out_nembed[(size_t)d * NEMB + k] = navg / cs[k];
    }
}

extern "C" void kernel_launch(void* const* d_in, const int* in_sizes, int n_in,
                              void* d_out, int out_size, void* d_ws, size_t ws_size,
                              hipStream_t stream) {
    const float* input        = (const float*)d_in[0];
    const float* embed        = (const float*)d_in[1];
    const float* cluster_size = (const float*)d_in[2];
    const float* embed_avg    = (const float*)d_in[3];

    float* out        = (float*)d_out;
    float* out_q      = out;                       // 16777216
    float* out_diff   = out + 16777216;            // 1
    float* out_ind    = out + 16777217;            // 65536
    float* out_ncs    = out + 16842753;            // 1024
    float* out_navg   = out + 16843777;            // 262144
    float* out_nembed = out + 17105921;            // 262144

    char* ws = (char*)d_ws;
    size_t o = 0;
    int*   w_ind      = (int*)(ws + o);   o += (size_t)NROWS * 4;
    float* w_embedT   = (float*)(ws + o); o += (size_t)DIM * NEMB * 4;
    float* w_enorm    = (float*)(ws + o); o += NEMB * 4;
    int*   w_counts   = (int*)(ws + o);   o += NEMB * 4;
    int*   w_offsets  = (int*)(ws + o);   o += NEMB * 4;
    int*   w_cursor   = (int*)(ws + o);   o += NEMB * 4;
    float* w_cs       = (float*)(ws + o); o += NEMB * 4;
    float* w_partials = (float*)(ws + o); o += 2048 * 4;
    int*   w_sorted   = (int*)(ws + o);   o += (size_t)NROWS * 4;
    int*   w_substart = (int*)(ws + o);   o += (NEMB + 4) * 4;
    float* w_partial  = (float*)(ws + o); o += (size_t)MAXSUB * DIM * 4;
    f16*   w_ehT      = (f16*)(ws + o);   o += (size_t)NEMB * 256 * 2;
    unsigned char* w_flags = (unsigned char*)(ws + o); o += NROWS;
    int*   w_flaglist = (int*)(ws + o);   o += (size_t)NROWS * 4;
    int*   w_nflag    = (int*)(ws + o);   o += 16;

    k_enorm<<<16, 256, 0, stream>>>(embed, w_enorm, w_counts, w_nflag);
    k_prep<<<dim3(32, 8), dim3(32, 8), 0, stream>>>(embed, w_embedT, w_ehT);
    k_argmin_mfma<<<NROWS / 64, 256, 0, stream>>>(input, w_ehT, w_enorm,
                                                  w_ind, out_ind, w_counts, w_flags);
    k_compact<<<NROWS / 256, 256, 0, stream>>>(w_flags, w_nflag, w_flaglist);
    k_fix<<<64, 256, 0, stream>>>(input, embed, w_enorm, w_flaglist, w_nflag,
                                  w_ind, out_ind, w_counts);
    k_quant<<<2048, 256, 0, stream>>>(input, w_embedT, w_ind, out_q, w_partials);
    k_scan<<<1, 1024, 0, stream>>>(w_counts, cluster_size, w_partials, w_offsets,
                                   w_cursor, w_substart, out_ncs, w_cs, out_diff);
    k_scatter<<<NROWS / 256, 256, 0, stream>>>(w_ind, w_cursor, w_sorted);
    k_psum<<<MAXSUB, 256, 0, stream>>>(input, w_sorted, w_counts, w_offsets,
                                       w_substart, w_partial);
    k_ema<<<DIM, 256, 0, stream>>>(w_partial, embed_avg, w_substart, w_cs,
                                   out_navg, out_nembed);
}

// Round 12
// 421.204 us; speedup vs baseline: 2.9003x; 2.9003x over previous
//
#include <hip/hip_runtime.h>
#include <float.h>

#define DECAY 0.99f
#define EPS 1e-5f
#define NROWS 65536
#define DIM 256
#define NEMB 1024
#define CH 64            // rows per sub-chunk in segmented reduction
#define MAXSUB 2048      // NROWS/CH + NEMB upper bound on total sub-chunks
#define WND 1.6f         // certificate window: > 2 * (2^-9 * ||x||max * ||e||max)

#define GLOBAL_AS __attribute__((address_space(1)))
#define LOCAL_AS  __attribute__((address_space(3)))

typedef _Float16 f16;
typedef _Float16 half8 __attribute__((ext_vector_type(8)));
typedef float f32x4 __attribute__((ext_vector_type(4)));

// ---------- K0a: ||e_k||^2 per code + zero counts + zero nflag ----------
__global__ __launch_bounds__(256) void k_enorm(const float* __restrict__ embed,
                                               float* __restrict__ enorm2,
                                               int* __restrict__ counts,
                                               int* __restrict__ nflag) {
    int kk = threadIdx.x & 63;
    int dg = threadIdx.x >> 6;              // 0..3
    int k  = blockIdx.x * 64 + kk;          // 16 blocks * 64 = 1024 codes
    float s = 0.f;
    for (int d = dg; d < DIM; d += 4) {
        float v = embed[(size_t)d * NEMB + k];
        s = fmaf(v, v, s);
    }
    __shared__ float red[4][64];
    red[dg][kk] = s;
    __syncthreads();
    if (dg == 0) enorm2[k] = red[0][kk] + red[1][kk] + red[2][kk] + red[3][kk];
    int gt = blockIdx.x * 256 + threadIdx.x;
    if (gt < NEMB) counts[gt] = 0;
    if (blockIdx.x == 0 && threadIdx.x == 0) nflag[0] = 0;
}

// ---------- K0b: fused transpose (embedT fp32) + f16-hi split (ehT [1024][256]) ----------
__global__ __launch_bounds__(256) void k_prep(const float* __restrict__ embed,
                                              float* __restrict__ embedT,
                                              f16* __restrict__ ehT) {
    __shared__ float tile[32][33];           // [d-local][c-local]
    int c0 = blockIdx.x * 32, d0 = blockIdx.y * 32;
    int tx = threadIdx.x, ty = threadIdx.y;  // 32 x 8
#pragma unroll
    for (int i = 0; i < 4; i++)
        tile[ty + 8 * i][tx] = embed[(size_t)(d0 + ty + 8 * i) * NEMB + c0 + tx];
    __syncthreads();
#pragma unroll
    for (int i = 0; i < 4; i++) {
        int c = c0 + ty + 8 * i;
        int d = d0 + tx;
        float v = tile[tx][ty + 8 * i];
        embedT[(size_t)c * DIM + d] = v;
        ehT[(size_t)c * 256 + d] = (f16)v;
    }
}

// ---------- K1: MFMA GEMM-argmin v9: 1-term f16 + 2nd-best certificate (UNCHANGED from R11) ----------
#define LDS_A  0        // 32KB
#define LDS_B0 32768    // 16KB (PV/PI/P2 overlay after the loop)
#define LDS_B1 49152    // 16KB
#define LDS_SZ 65536

__global__ __launch_bounds__(256, 2) void k_argmin_mfma(const float* __restrict__ input,
                                                        const f16* __restrict__ ehT,
                                                        const float* __restrict__ enorm2,
                                                        int* __restrict__ ind,
                                                        float* __restrict__ out_ind,
                                                        int* __restrict__ counts,
                                                        unsigned char* __restrict__ flags) {
    __shared__ char lds[LDS_SZ];
    const int tid  = threadIdx.x;
    const int lane = tid & 63;
    const int w    = tid >> 6;        // wave 0..3: cols w*64 within each 256-slab
    const int rb   = blockIdx.x * 64;
    const int l15  = lane & 15;
    const int lkh  = lane >> 4;       // 0..3
    const int slot_log   = (lane & 3) ^ ((lane >> 3) & 3);
    const int gl_laneoff = (lane >> 2) * 256 + slot_log * 8;   // f16 units (row len 256)

    float e2a[4][4];
#pragma unroll
    for (int s = 0; s < 4; ++s)
#pragma unroll
        for (int fc = 0; fc < 4; ++fc)
            e2a[s][fc] = enorm2[s * 256 + w * 64 + fc * 16 + l15];

#pragma unroll
    for (int i = 0; i < 4; i++) {
        int chunk = w * 4 + i;                           // 16 chunks of 16 cols
        const f16* src = ehT + (size_t)chunk * 4096 + gl_laneoff;
        __builtin_amdgcn_global_load_lds((const GLOBAL_AS unsigned*)src,
            (LOCAL_AS unsigned*)(lds + LDS_B0 + chunk * 1024), 16, 0, 0);
    }

#pragma unroll
    for (int it4 = 0; it4 < 4; it4++) {
        int task = tid + 256 * it4;          // 0..1023
        int row = task >> 4, ch = task & 15; // ch = 16-d chunk
        const float4* g = (const float4*)(input + (size_t)(rb + row) * DIM + ch * 16);
        float fv[16];
        *(float4*)(fv + 0)  = g[0];
        *(float4*)(fv + 4)  = g[1];
        *(float4*)(fv + 8)  = g[2];
        *(float4*)(fv + 12) = g[3];
        half8 hh[2];
#pragma unroll
        for (int u = 0; u < 2; u++)
#pragma unroll
            for (int e = 0; e < 8; e++) hh[u][e] = (f16)fv[u * 8 + e];
        int rbase = row * 512;
        int sw = (row & 7) << 4;
        *(half8*)(lds + LDS_A + rbase + (((ch * 2    ) * 16) ^ sw)) = hh[0];
        *(half8*)(lds + LDS_A + rbase + (((ch * 2 + 1) * 16) ^ sw)) = hh[1];
    }
    __syncthreads();   // A staged + B0 landed

    float bv[16], b2[16];
    int   bi[16];
#pragma unroll
    for (int q = 0; q < 16; q++) { bv[q] = FLT_MAX; b2[q] = FLT_MAX; bi[q] = 0x7fffffff; }

    f32x4 acc[4][4];
    int p = 0;
    for (int it = 0; it < 32; ++it) {
        const int ct = it >> 3, kt = it & 7;
        if (kt == 0) {
#pragma unroll
            for (int fr = 0; fr < 4; fr++)
#pragma unroll
                for (int fc = 0; fc < 4; fc++) acc[fr][fc] = (f32x4){0.f, 0.f, 0.f, 0.f};
        }
        if (it < 31) {
            int itn = it + 1;
            int ct2 = itn >> 3, kt2 = itn & 7;
            const f16* base = ehT + (size_t)ct2 * 65536 + kt2 * 32 + gl_laneoff;
            char* dstb = lds + (p ? LDS_B0 : LDS_B1);
#pragma unroll
            for (int i = 0; i < 4; i++) {
                int chunk = w * 4 + i;
                __builtin_amdgcn_global_load_lds(
                    (const GLOBAL_AS unsigned*)(base + (size_t)chunk * 4096),
                    (LOCAL_AS unsigned*)(dstb + chunk * 1024), 16, 0, 0);
            }
        }
        const char* Bb = lds + (p ? LDS_B1 : LDS_B0);
        half8 af[4], bf[4];
#pragma unroll
        for (int f = 0; f < 4; f++) {
            int row = f * 16 + l15;
            af[f] = *(const half8*)(lds + LDS_A + row * 512 +
                                    (((kt * 4 + lkh) * 16) ^ ((row & 7) << 4)));
        }
#pragma unroll
        for (int f = 0; f < 4; f++) {
            int col = w * 64 + f * 16 + l15;
            bf[f] = *(const half8*)(Bb + col * 64 + ((lkh * 16) ^ (((col >> 1) & 3) << 4)));
        }
        __builtin_amdgcn_s_setprio(1);
#pragma unroll
        for (int fr = 0; fr < 4; fr++)
#pragma unroll
            for (int fc = 0; fc < 4; fc++)
                acc[fr][fc] = __builtin_amdgcn_mfma_f32_16x16x32_f16(
                    af[fr], bf[fc], acc[fr][fc], 0, 0, 0);
        __builtin_amdgcn_s_setprio(0);
        if (kt == 7) {
#pragma unroll
            for (int fc = 0; fc < 4; fc++) {
                int col = ct * 256 + w * 64 + fc * 16 + l15;
                float e2 = e2a[ct][fc];
#pragma unroll
                for (int fr = 0; fr < 4; fr++)
#pragma unroll
                    for (int r = 0; r < 4; r++) {
                        float s = fmaf(-2.f, acc[fr][fc][r], e2);
                        int q = fr * 4 + r;
                        if (s < bv[q]) { b2[q] = bv[q]; bv[q] = s; bi[q] = col; }
                        else if (s < b2[q]) b2[q] = s;
                    }
            }
        }
        __syncthreads();
        p ^= 1;
    }

#pragma unroll
    for (int q = 0; q < 16; q++) {
        float v1 = bv[q], v2 = b2[q]; int i1 = bi[q];
#pragma unroll
        for (int m = 1; m <= 8; m <<= 1) {
            float ov1 = __shfl_xor(v1, m, 64);
            int   oi1 = __shfl_xor(i1, m, 64);
            float ov2 = __shfl_xor(v2, m, 64);
            if (ov1 < v1 || (ov1 == v1 && oi1 < i1)) {
                v2 = fminf(v1, ov2); v1 = ov1; i1 = oi1;
            } else {
                v2 = fminf(v2, ov1);
            }
        }
        bv[q] = v1; bi[q] = i1; b2[q] = v2;
    }
    float* PV = (float*)(lds + LDS_B0);          // [64][4]
    int*   PI = (int*)(lds + LDS_B0 + 1024);     // [64][4]
    float* P2 = (float*)(lds + LDS_B0 + 2048);   // [64][4]
    if (l15 == 0) {
#pragma unroll
        for (int fr = 0; fr < 4; fr++)
#pragma unroll
            for (int r = 0; r < 4; r++) {
                int rrow = fr * 16 + lkh * 4 + r;
                PV[rrow * 4 + w] = bv[fr * 4 + r];
                PI[rrow * 4 + w] = bi[fr * 4 + r];
                P2[rrow * 4 + w] = b2[fr * 4 + r];
            }
    }
    __syncthreads();
    if (tid < 64) {
        float v1 = PV[tid * 4]; int i1 = PI[tid * 4]; float v2 = P2[tid * 4];
#pragma unroll
        for (int t = 1; t < 4; t++) {
            float ov1 = PV[tid * 4 + t]; int oi1 = PI[tid * 4 + t]; float ov2 = P2[tid * 4 + t];
            if (ov1 < v1 || (ov1 == v1 && oi1 < i1)) {
                v2 = fminf(v1, ov2); v1 = ov1; i1 = oi1;
            } else {
                v2 = fminf(v2, ov1);
            }
        }
        int fl = (v2 - v1 <= WND) ? 1 : 0;
        ind[rb + tid] = i1;
        out_ind[rb + tid] = (float)i1;
        flags[rb + tid] = (unsigned char)fl;
        if (!fl) atomicAdd(&counts[i1], 1);   // flagged rows counted in k_fix
    }
}

// ---------- K1b: compact flagged rows (order-free; per-row results independent) ----------
__global__ __launch_bounds__(256) void k_compact(const unsigned char* __restrict__ flags,
                                                 int* __restrict__ nflag,
                                                 int* __restrict__ flaglist) {
    int i = blockIdx.x * 256 + threadIdx.x;
    if (flags[i]) { int p = atomicAdd(nflag, 1); flaglist[p] = i; }
}

// ---------- K1c: exact fp32 re-resolve. One 8-row group per block, grid 8192, early-exit. ----------
__global__ __launch_bounds__(256) void k_fix(const float* __restrict__ input,
                                             const float* __restrict__ embed,
                                             const float* __restrict__ enorm2,
                                             const int* __restrict__ flaglist,
                                             const int* __restrict__ nflag,
                                             int* __restrict__ ind,
                                             float* __restrict__ out_ind,
                                             int* __restrict__ counts) {
    const int total = nflag[0];
    const int base  = blockIdx.x * 8;
    if (base >= total) return;
    const int nr = min(8, total - base);
    __shared__ float xs[8][256];
    __shared__ float rv[8][256];
    __shared__ int   ri[8][256];
    const int t = threadIdx.x;
    for (int j = 0; j < nr; j++) {
        int row = flaglist[base + j];
        xs[j][t] = input[(size_t)row * DIM + t];
    }
    for (int j = nr; j < 8; j++) xs[j][t] = 0.f;
    __syncthreads();

    float best[8]; int bidx[8];
#pragma unroll
    for (int j = 0; j < 8; j++) { best[j] = FLT_MAX; bidx[j] = 0x7fffffff; }

    for (int cc = 0; cc < 4; cc++) {
        const int c = cc * 256 + t;
        float s[8];
#pragma unroll
        for (int j = 0; j < 8; j++) s[j] = 0.f;
        for (int d0 = 0; d0 < 256; d0 += 8) {
            float ev[8];
#pragma unroll
            for (int u = 0; u < 8; u++)
                ev[u] = embed[(size_t)(d0 + u) * NEMB + c];   // 8 independent coalesced loads
#pragma unroll
            for (int u = 0; u < 8; u++)
#pragma unroll
                for (int j = 0; j < 8; j++)
                    s[j] = fmaf(xs[j][d0 + u], ev[u], s[j]);  // LDS broadcast reads
        }
        const float e2 = enorm2[c];
#pragma unroll
        for (int j = 0; j < 8; j++) {
            float dist = fmaf(-2.f, s[j], e2);
            if (dist < best[j]) { best[j] = dist; bidx[j] = c; }  // cc asc => lowest idx on tie
        }
    }
    // parallel 8-row tree reduction over 256 threads
#pragma unroll
    for (int j = 0; j < 8; j++) { rv[j][t] = best[j]; ri[j][t] = bidx[j]; }
    __syncthreads();
    for (int off = 128; off > 0; off >>= 1) {
        if (t < off) {
#pragma unroll
            for (int j = 0; j < 8; j++) {
                float v = rv[j][t + off]; int i2 = ri[j][t + off];
                if (v < rv[j][t] || (v == rv[j][t] && i2 < ri[j][t])) {
                    rv[j][t] = v; ri[j][t] = i2;
                }
            }
        }
        __syncthreads();
    }
    if (t < nr) {
        int row = flaglist[base + t];
        int bi0 = ri[t][0];
        ind[row] = bi0;
        out_ind[row] = (float)bi0;
        atomicAdd(&counts[bi0], 1);
    }
}

// ---------- K2: quantize_st output + per-block diff partials ----------
__global__ __launch_bounds__(256) void k_quant(const float* __restrict__ input,
                                               const float* __restrict__ embedT,
                                               const int* __restrict__ ind,
                                               float* __restrict__ out_q,
                                               float* __restrict__ partials) {
    const int tid = threadIdx.x;
    const unsigned gid = blockIdx.x * 256 + tid;
    float s = 0.f;
#pragma unroll
    for (int j = 0; j < 8; j++) {
        size_t i4 = (size_t)gid + (size_t)j * 524288u;   // 4194304 float4 total
        int row = (int)(i4 >> 6);
        int d4  = (int)(i4 & 63);
        float4 iv = *reinterpret_cast<const float4*>(input + i4 * 4);
        int k = ind[row];
        float4 qv = *reinterpret_cast<const float4*>(embedT + (size_t)k * DIM + d4 * 4);
        float dx = qv.x - iv.x, dy = qv.y - iv.y, dz = qv.z - iv.z, dw = qv.w - iv.w;
        float4 ov;
        ov.x = iv.x + dx; ov.y = iv.y + dy; ov.z = iv.z + dz; ov.w = iv.w + dw;
        *reinterpret_cast<float4*>(out_q + i4 * 4) = ov;
        s += dx * dx + dy * dy + dz * dz + dw * dw;
    }
    __shared__ float red[256];
    red[tid] = s;
    __syncthreads();
    for (int off = 128; off > 0; off >>= 1) {
        if (tid < off) red[tid] += red[tid + off];
        __syncthreads();
    }
    if (tid == 0) partials[blockIdx.x] = red[0];
}

// ---------- K4: diff finalize + scans + ncs, n, cs ----------
__global__ __launch_bounds__(1024) void k_scan(const int* __restrict__ counts,
                                               const float* __restrict__ cluster_size,
                                               const float* __restrict__ qpartials,
                                               int* __restrict__ offsets,
                                               int* __restrict__ cursor,
                                               int* __restrict__ substart,
                                               float* __restrict__ out_ncs,
                                               float* __restrict__ cs,
                                               float* __restrict__ out_diff) {
    __shared__ int sh[NEMB];
    __shared__ float shf[NEMB];
    int tid = threadIdx.x;
    shf[tid] = qpartials[tid] + qpartials[tid + 1024];
    __syncthreads();
    for (int off = 512; off > 0; off >>= 1) {
        if (tid < off) shf[tid] += shf[tid + off];
        __syncthreads();
    }
    if (tid == 0) out_diff[0] = shf[0] / 16777216.0f;
    __syncthreads();
    int c = counts[tid];
    sh[tid] = c;
    __syncthreads();
    for (int off = 1; off < NEMB; off <<= 1) {
        int t = (tid >= off) ? sh[tid - off] : 0;
        __syncthreads();
        sh[tid] += t;
        __syncthreads();
    }
    int excl = sh[tid] - c;
    offsets[tid] = excl;
    cursor[tid]  = excl;
    int sc = (c + CH - 1) / CH;
    __syncthreads();
    sh[tid] = sc;
    __syncthreads();
    for (int off = 1; off < NEMB; off <<= 1) {
        int t = (tid >= off) ? sh[tid - off] : 0;
        __syncthreads();
        sh[tid] += t;
        __syncthreads();
    }
    substart[tid] = sh[tid] - sc;
    if (tid == NEMB - 1) substart[NEMB] = sh[tid];
    float ncs = cluster_size[tid] * DECAY + (1.f - DECAY) * (float)c;
    out_ncs[tid] = ncs;
    shf[tid] = ncs;
    __syncthreads();
    for (int off = 512; off > 0; off >>= 1) {
        if (tid < off) shf[tid] += shf[tid + off];
        __syncthreads();
    }
    float n = shf[0];
    cs[tid] = (ncs + EPS) / (n + NEMB * EPS) * n;
}

// ---------- K5: scatter rows by cluster ----------
__global__ __launch_bounds__(256) void k_scatter(const int* __restrict__ ind,
                                                 int* __restrict__ cursor,
                                                 int* __restrict__ sorted) {
    int i = blockIdx.x * 256 + threadIdx.x;
    int k = ind[i];
    int pos = atomicAdd(&cursor[k], 1);
    sorted[pos] = i;
}

// ---------- K6a: balanced partial sums. block = one 64-row sub-chunk ----------
__global__ __launch_bounds__(256) void k_psum(const float* __restrict__ input,
                                              const int* __restrict__ sorted,
                                              const int* __restrict__ counts,
                                              const int* __restrict__ offsets,
                                              const int* __restrict__ substart,
                                              float* __restrict__ partial) {
    const int b = blockIdx.x;
    if (b >= substart[NEMB]) return;
    int lo = 0, hi = NEMB;
    while (hi - lo > 1) {
        int mid = (lo + hi) >> 1;
        if (substart[mid] <= b) lo = mid; else hi = mid;
    }
    const int k     = lo;
    const int chunk = b - substart[k];
    const int cnt   = counts[k];
    const int base  = offsets[k] + chunk * CH;
    const int lim   = min(CH, cnt - chunk * CH);
    const int d     = threadIdx.x;
    float s = 0.f;
    for (int i = 0; i < lim; i++) {
        int row = sorted[base + i];
        s += input[(size_t)row * DIM + d];
    }
    partial[(size_t)b * DIM + d] = s;
}

// ---------- K6b: per-cluster combine (fixed order) + EMA + new_embed ----------
__global__ __launch_bounds__(256) void k_ema(const float* __restrict__ partial,
                                             const float* __restrict__ embed_avg,
                                             const int* __restrict__ substart,
                                             const float* __restrict__ cs,
                                             float* __restrict__ out_navg,
                                             float* __restrict__ out_nembed) {
    const int d = blockIdx.x;
    const int t = threadIdx.x;
#pragma unroll
    for (int i = 0; i < 4; i++) {
        int k = t + 256 * i;
        int s0 = substart[k], s1 = substart[k + 1];
        float s = 0.f;
        for (int sub = s0; sub < s1; sub++)
            s += partial[(size_t)sub * DIM + d];
        float navg = embed_avg[(size_t)d * NEMB + k] * (DECAY * DECAY) + (1.f - DECAY) * s;
        out_navg[(size_t)d * NEMB + k] = navg;
        out_nembed[(size_t)d * NEMB + k] = navg / cs[k];
    }
}

extern "C" void kernel_launch(void* const* d_in, const int* in_sizes, int n_in,
                              void* d_out, int out_size, void* d_ws, size_t ws_size,
                              hipStream_t stream) {
    const float* input        = (const float*)d_in[0];
    const float* embed        = (const float*)d_in[1];
    const float* cluster_size = (const float*)d_in[2];
    const float* embed_avg    = (const float*)d_in[3];

    float* out        = (float*)d_out;
    float* out_q      = out;                       // 16777216
    float* out_diff   = out + 16777216;            // 1
    float* out_ind    = out + 16777217;            // 65536
    float* out_ncs    = out + 16842753;            // 1024
    float* out_navg   = out + 16843777;            // 262144
    float* out_nembed = out + 17105921;            // 262144

    char* ws = (char*)d_ws;
    size_t o = 0;
    int*   w_ind      = (int*)(ws + o);   o += (size_t)NROWS * 4;
    float* w_embedT   = (float*)(ws + o); o += (size_t)DIM * NEMB * 4;
    float* w_enorm    = (float*)(ws + o); o += NEMB * 4;
    int*   w_counts   = (int*)(ws + o);   o += NEMB * 4;
    int*   w_offsets  = (int*)(ws + o);   o += NEMB * 4;
    int*   w_cursor   = (int*)(ws + o);   o += NEMB * 4;
    float* w_cs       = (float*)(ws + o); o += NEMB * 4;
    float* w_partials = (float*)(ws + o); o += 2048 * 4;
    int*   w_sorted   = (int*)(ws + o);   o += (size_t)NROWS * 4;
    int*   w_substart = (int*)(ws + o);   o += (NEMB + 4) * 4;
    float* w_partial  = (float*)(ws + o); o += (size_t)MAXSUB * DIM * 4;
    f16*   w_ehT      = (f16*)(ws + o);   o += (size_t)NEMB * 256 * 2;
    unsigned char* w_flags = (unsigned char*)(ws + o); o += NROWS;
    int*   w_flaglist = (int*)(ws + o);   o += (size_t)NROWS * 4;
    int*   w_nflag    = (int*)(ws + o);   o += 16;

    k_enorm<<<16, 256, 0, stream>>>(embed, w_enorm, w_counts, w_nflag);
    k_prep<<<dim3(32, 8), dim3(32, 8), 0, stream>>>(embed, w_embedT, w_ehT);
    k_argmin_mfma<<<NROWS / 64, 256, 0, stream>>>(input, w_ehT, w_enorm,
                                                  w_ind, out_ind, w_counts, w_flags);
    k_compact<<<NROWS / 256, 256, 0, stream>>>(w_flags, w_nflag, w_flaglist);
    k_fix<<<NROWS / 8, 256, 0, stream>>>(input, embed, w_enorm, w_flaglist, w_nflag,
                                         w_ind, out_ind, w_counts);
    k_quant<<<2048, 256, 0, stream>>>(input, w_embedT, w_ind, out_q, w_partials);
    k_scan<<<1, 1024, 0, stream>>>(w_counts, cluster_size, w_partials, w_offsets,
                                   w_cursor, w_substart, out_ncs, w_cs, out_diff);
    k_scatter<<<NROWS / 256, 256, 0, stream>>>(w_ind, w_cursor, w_sorted);
    k_psum<<<MAXSUB, 256, 0, stream>>>(input, w_sorted, w_counts, w_offsets,
                                       w_substart, w_partial);
    k_ema<<<DIM, 256, 0, stream>>>(w_partial, embed_avg, w_substart, w_cs,
                                   out_navg, out_nembed);
}